// Round 16
// baseline (3005.370 us; speedup 1.0000x reference)
//
#include <hip/hip_runtime.h>
#include <cstdint>
#include <cstddef>

typedef _Float16 f16;
typedef _Float16 f16x8 __attribute__((ext_vector_type(8)));
typedef float f32x4 __attribute__((ext_vector_type(4)));
typedef unsigned int u32;
typedef unsigned short u16;
typedef u32 u32x4 __attribute__((ext_vector_type(4)));

#define NB 256
#define NT 256
#define ND 128
#define NH 512
#define NG 1536
#define NOUT 24
#define PL (NB * NH)  // one packed exchange plane (u32 elements)

__device__ __forceinline__ float fsig(float x) {
  float e = __expf(-x);
  return __fdividef(1.0f, 1.0f + e);
}
__device__ __forceinline__ float ftanh(float x) {
  float ax = __builtin_fabsf(x);
  float e = __expf(-2.0f * ax);
  float t = __fdividef(1.0f - e, 1.0f + e);
  return __builtin_copysignf(t, x);
}

__global__ void k_f32_to_f16(const float* __restrict__ in, f16* __restrict__ out, int n) {
  int stride = gridDim.x * blockDim.x;
  for (int i = blockIdx.x * blockDim.x + threadIdx.x; i < n; i += stride)
    out[i] = (f16)in[i];
}

// async global->LDS, 16B per lane (dest = wave-uniform base + lane*16)
__device__ __forceinline__ void gl16(const f16* g, f16* l) {
  __builtin_amdgcn_global_load_lds(
      (const __attribute__((address_space(1))) u32*)(const void*)g,
      (__attribute__((address_space(3))) u32*)(void*)l, 16, 0, 0);
}

// ---- m97-style gx GEMM (proven r14): gx = A @ W^T + b. BM=BN=128, BK=32.
template <int K>
__global__ __launch_bounds__(256) void k_gemm2(
    const f16* __restrict__ A, const f16* __restrict__ W,
    const float* __restrict__ bias, f16* __restrict__ gx, int t0, int tsh) {
  __shared__ f16 As[128 * 32];
  __shared__ f16 Bs[128 * 32];
  const int tid = threadIdx.x;
  const int wave = tid >> 6, lane = tid & 63;
  const int wm = wave >> 1, wn = wave & 1;
  const int m0 = blockIdx.x * 128;
  const int n0 = blockIdx.y * 128;
  const int tmask = (1 << tsh) - 1;

  const int r0 = tid >> 2;
  const int swzs = (r0 >> 1) & 3;
  const int csrc = ((tid & 3) ^ swzs) * 8;
  const int ga0 = m0 + r0, ga1 = m0 + r0 + 64;
  const int gr0 = ((ga0 >> tsh) << 8) + t0 + (ga0 & tmask);
  const int gr1 = ((ga1 >> tsh) << 8) + t0 + (ga1 & tmask);
  const f16* a0 = A + (size_t)gr0 * K + csrc;
  const f16* a1 = A + (size_t)gr1 * K + csrc;
  const f16* b0 = W + (size_t)(n0 + r0) * K + csrc;
  const f16* b1 = W + (size_t)(n0 + r0 + 64) * K + csrc;
  f16* asb = As + wave * 512;
  f16* bsb = Bs + wave * 512;

  const int lr = lane & 15;
  const int kg = lane >> 4;
  const int swzr = ((lr >> 1) & 3);
  const int koff = (kg ^ swzr) * 8;

  f32x4 acc[4][4];
#pragma unroll
  for (int i = 0; i < 4; i++)
#pragma unroll
    for (int j = 0; j < 4; j++) acc[i][j] = (f32x4){0.f, 0.f, 0.f, 0.f};

  for (int k0 = 0; k0 < K; k0 += 32) {
    gl16(a0 + k0, asb);
    gl16(a1 + k0, asb + 2048);
    gl16(b0 + k0, bsb);
    gl16(b1 + k0, bsb + 2048);
    asm volatile("s_waitcnt vmcnt(0)" ::: "memory");
    __syncthreads();
    f16x8 af[4], bf[4];
#pragma unroll
    for (int i = 0; i < 4; i++)
      af[i] = *(const f16x8*)(As + (wm * 64 + i * 16 + lr) * 32 + koff);
#pragma unroll
    for (int j = 0; j < 4; j++)
      bf[j] = *(const f16x8*)(Bs + (wn * 64 + j * 16 + lr) * 32 + koff);
#pragma unroll
    for (int i = 0; i < 4; i++)
#pragma unroll
      for (int j = 0; j < 4; j++)
        acc[i][j] = __builtin_amdgcn_mfma_f32_16x16x32_f16(af[i], bf[j], acc[i][j], 0, 0, 0);
    __syncthreads();
  }
  const int rowb = (lane >> 4) * 4;
#pragma unroll
  for (int j = 0; j < 4; j++) {
    int col = n0 + wn * 64 + j * 16 + lr;
    float bv = bias[col];
#pragma unroll
    for (int i = 0; i < 4; i++) {
      int row = m0 + wm * 64 + i * 16 + rowb;
#pragma unroll
      for (int rr = 0; rr < 4; rr++)
        gx[(size_t)(row + rr) * NG + col] = (f16)(acc[i][j][rr] + bv);
    }
  }
}

// issue one 4-kk batch (8 dwordx4, system-coherent) from packed plane
#define ISSUE4K(qarr, kkb)                                               \
  _Pragma("unroll") for (int u_ = 0; u_ < 4; u_++) {                     \
    const u32* pp_ = hq + (kkb + u_) * 32 + lkh * 8;                     \
    asm volatile("global_load_dwordx4 %0, %1, off sc0 sc1"               \
                 : "=v"(qarr[2 * u_]) : "v"(pp_));                       \
    asm volatile("global_load_dwordx4 %0, %1, off sc0 sc1"               \
                 : "=v"(qarr[2 * u_ + 1]) : "v"(pp_ + 4));               \
  }

// consume one 4-kk batch: unpack hi/lo, 12 MFMA per kk. n-gate B-frags come
// from registers (bnO/bnX, statically indexed by nb0+u_); r,z from LDS.
#define CONS4K(qarr, kkb, nb0)                                                       \
  _Pragma("unroll") for (int u_ = 0; u_ < 4; u_++) {                                 \
    const int kk_ = kkb + u_;                                                        \
    union { u32 w[4]; f16x8 v; } AH_, AL_;                                           \
    AH_.w[0] = __builtin_amdgcn_perm(qarr[2*u_][1],   qarr[2*u_][0],   0x05040100u); \
    AH_.w[1] = __builtin_amdgcn_perm(qarr[2*u_][3],   qarr[2*u_][2],   0x05040100u); \
    AH_.w[2] = __builtin_amdgcn_perm(qarr[2*u_+1][1], qarr[2*u_+1][0], 0x05040100u); \
    AH_.w[3] = __builtin_amdgcn_perm(qarr[2*u_+1][3], qarr[2*u_+1][2], 0x05040100u); \
    AL_.w[0] = __builtin_amdgcn_perm(qarr[2*u_][1],   qarr[2*u_][0],   0x07060302u); \
    AL_.w[1] = __builtin_amdgcn_perm(qarr[2*u_][3],   qarr[2*u_][2],   0x07060302u); \
    AL_.w[2] = __builtin_amdgcn_perm(qarr[2*u_+1][1], qarr[2*u_+1][0], 0x07060302u); \
    AL_.w[3] = __builtin_amdgcn_perm(qarr[2*u_+1][3], qarr[2*u_+1][2], 0x07060302u); \
    const int co_ = (((kk_ * 4 + lkh) ^ swz) << 3);                                  \
    f16x8 bro_ = *(const f16x8*)(wro_ + co_);                                        \
    f16x8 bzo_ = *(const f16x8*)(wzo_ + co_);                                        \
    f16x8 brx_ = *(const f16x8*)(wrx_ + co_);                                        \
    f16x8 bzx_ = *(const f16x8*)(wzx_ + co_);                                        \
    f16x8 bno_ = bnO[nb0 + u_];                                                      \
    f16x8 bnx_ = bnX[nb0 + u_];                                                      \
    aRo = __builtin_amdgcn_mfma_f32_16x16x32_f16(AH_.v, bro_, aRo, 0, 0, 0);         \
    aZo = __builtin_amdgcn_mfma_f32_16x16x32_f16(AH_.v, bzo_, aZo, 0, 0, 0);         \
    aNo = __builtin_amdgcn_mfma_f32_16x16x32_f16(AH_.v, bno_, aNo, 0, 0, 0);         \
    aRx = __builtin_amdgcn_mfma_f32_16x16x32_f16(AH_.v, brx_, aRx, 0, 0, 0);         \
    aZx = __builtin_amdgcn_mfma_f32_16x16x32_f16(AH_.v, bzx_, aZx, 0, 0, 0);         \
    aNx = __builtin_amdgcn_mfma_f32_16x16x32_f16(AH_.v, bnx_, aNx, 0, 0, 0);         \
    aRo = __builtin_amdgcn_mfma_f32_16x16x32_f16(AL_.v, bro_, aRo, 0, 0, 0);         \
    aZo = __builtin_amdgcn_mfma_f32_16x16x32_f16(AL_.v, bzo_, aZo, 0, 0, 0);         \
    aNo = __builtin_amdgcn_mfma_f32_16x16x32_f16(AL_.v, bno_, aNo, 0, 0, 0);         \
    aRx = __builtin_amdgcn_mfma_f32_16x16x32_f16(AL_.v, brx_, aRx, 0, 0, 0);         \
    aZx = __builtin_amdgcn_mfma_f32_16x16x32_f16(AL_.v, bzx_, aZx, 0, 0, 0);         \
    aNx = __builtin_amdgcn_mfma_f32_16x16x32_f16(AL_.v, bnx_, aNx, 0, 0, 0);         \
  }

struct RecUnit {
  const f16* gx; const f16* whh; const float* bhh;
  u32* exq; u32* fl; int t0; int bar_base;
};

// ---- GRU recurrence (r12 core + per-wave flags). <=3 independent 128-block
// units per launch. n-gate weights register-resident; r,z in LDS (64KB).
// PER-WAVE flags: each wave drains only its own stores then publishes its own
// flag (4/block, 64/group, one 256B span); no block barrier in the step tail.
// WAR safety: a wave reaches its t+2 plds write / plane store only after its
// poll saw every wave's flag(t+1), and each wave flags only after its plds
// read + plane reads -- the flag fabric subsumes the removed __syncthreads.
__global__ __launch_bounds__(256, 2) void k_rec(
    RecUnit u0, RecUnit u1, RecUnit u2, f16* __restrict__ h, int Tc) {
  __shared__ f16 wlds[64 * 512];
  __shared__ float plds[2][2][64][12];
  RecUnit U = u0;
  const int ui = blockIdx.x >> 7;
  if (ui == 1) U = u1;
  if (ui == 2) U = u2;
  const int bid = blockIdx.x & 127;
  const f16* __restrict__ gx = U.gx;
  u32* __restrict__ exq = U.exq;
  const int t0 = U.t0, bar_base = U.bar_base;
  const int tid = threadIdx.x;
  const int g = bid >> 4;
  const int cs = bid & 15;
  const int b0 = g * 32, c0 = cs * 32;
  const int lane = tid & 63, wave = tid >> 6;
  const int wm = wave >> 1, ks = wave & 1;
  const int lr = lane & 15, lkh = lane >> 4;
  const int first = (t0 == 0) ? 1 : 0;
  const int jo = ks * 16 + lr;
  const int jx = (1 - ks) * 16 + lr;
  const int ks8 = ks * 8;

  // n-gate weights -> registers (issue first; overlaps LDS staging)
  f16x8 bnO[8], bnX[8];
  {
    const f16* wb = U.whh + (size_t)(2 * NH + c0) * NH + (size_t)ks8 * 32 + lkh * 8;
    const f16* wO = wb + (size_t)jo * NH;
    const f16* wX = wb + (size_t)jx * NH;
#pragma unroll
    for (int i = 0; i < 8; i++) {
      bnO[i] = *(const f16x8*)(wO + i * 32);
      bnX[i] = *(const f16x8*)(wX + i * 32);
    }
  }
  // r,z gates -> LDS (swizzled 16B chunks)
  for (int idx = tid; idx < 64 * 64; idx += 256) {
    int lrw = idx >> 6, c = idx & 63;
    int grow = (lrw >> 5) * NH + c0 + (lrw & 31);
    f16x8 v = *(const f16x8*)(U.whh + (size_t)grow * NH + c * 8);
    *(f16x8*)(wlds + lrw * 512 + ((c ^ (lrw & 7)) << 3)) = v;
  }
  __syncthreads();

  const int j = c0 + jo;
  const float bh_r = U.bhh[j], bh_z = U.bhh[NH + j], bh_n = U.bhh[2 * NH + j];
  const int arow = b0 + wm * 16 + lr;
  const int rowbase = b0 + wm * 16 + lkh * 4;
  const int swz = lr & 7;
  const f16* wro_ = wlds + jo * 512;
  const f16* wzo_ = wlds + (32 + jo) * 512;
  const f16* wrx_ = wlds + jx * 512;
  const f16* wzx_ = wlds + (32 + jx) * 512;
  u32* myflag = U.fl + g * 64 + cs * 4 + wave;  // per-wave flag
  u32* gflags = U.fl + g * 64;                  // 64 flags, 256B span

  union PK2 { u32 u; f16 hh[2]; };

  float hold[4];
  if (first) {
#pragma unroll
    for (int r = 0; r < 4; r++) hold[r] = 0.f;
  } else {
#pragma unroll
    for (int r = 0; r < 4; r++) {
      PK2 pk;
      pk.u = __hip_atomic_load(exq + (size_t)(rowbase + r) * NH + j,
                               __ATOMIC_RELAXED, __HIP_MEMORY_SCOPE_AGENT);
      hold[r] = (float)pk.hh[0] + (float)pk.hh[1];
    }
  }

  float xr[4], xz[4], xn[4];
#pragma unroll
  for (int r = 0; r < 4; r++) {
    const f16* gp = gx + ((size_t)(rowbase + r) * Tc) * NG + j;
    xr[r] = (float)gp[0]; xz[r] = (float)gp[NH]; xn[r] = (float)gp[2 * NH];
  }

  int cur = 0;
  for (int t = 0; t < Tc; t++) {
    f32x4 aRo = {0.f, 0.f, 0.f, 0.f}, aZo = {0.f, 0.f, 0.f, 0.f}, aNo = {0.f, 0.f, 0.f, 0.f};
    f32x4 aRx = {0.f, 0.f, 0.f, 0.f}, aZx = {0.f, 0.f, 0.f, 0.f}, aNx = {0.f, 0.f, 0.f, 0.f};
    if (t > 0 || !first) {
      const u32* hq = exq + (size_t)cur * PL + (size_t)arow * NH;
      u32x4 q0[8], q1[8];
      ISSUE4K(q0, ks8);
      ISSUE4K(q1, ks8 + 4);
      asm volatile("s_waitcnt vmcnt(8)" ::: "memory");
      __builtin_amdgcn_sched_barrier(0);
      CONS4K(q0, ks8, 0);
      asm volatile("s_waitcnt vmcnt(0)" ::: "memory");
      __builtin_amdgcn_sched_barrier(0);
      CONS4K(q1, ks8 + 4, 4);
      float* ps = &plds[wm][ks][lane][0];
#pragma unroll
      for (int i = 0; i < 4; i++) {
        ps[i] = aRx[i]; ps[4 + i] = aZx[i]; ps[8 + i] = aNx[i];
      }
      __syncthreads();
      const float* pr = &plds[wm][1 - ks][lane][0];
#pragma unroll
      for (int i = 0; i < 4; i++) {
        aRo[i] += pr[i]; aZo[i] += pr[4 + i]; aNo[i] += pr[8 + i];
      }
    }
    u32* outq = exq + (size_t)(cur ^ 1) * PL;
    f16 hhi_s[4];
#pragma unroll
    for (int r = 0; r < 4; r++) {
      float rg = fsig(xr[r] + aRo[r] + bh_r);
      float zg = fsig(xz[r] + aZo[r] + bh_z);
      float ng = ftanh(xn[r] + rg * (aNo[r] + bh_n));
      float hnew = ng + zg * (hold[r] - ng);
      hold[r] = hnew;
      PK2 pk;
      pk.hh[0] = (f16)hnew;
      pk.hh[1] = (f16)(hnew - (float)pk.hh[0]);
      hhi_s[r] = pk.hh[0];
      __hip_atomic_store(outq + (size_t)(rowbase + r) * NH + j, pk.u,
                         __ATOMIC_RELAXED, __HIP_MEMORY_SCOPE_AGENT);
    }
    if (t < Tc - 1) {
      // per-wave: drain own exchange stores, publish own flag. No block barrier.
      asm volatile("s_waitcnt vmcnt(0)" ::: "memory");
      if (lane == 0)
        __hip_atomic_store(myflag, (u32)(bar_base + t + 1),
                           __ATOMIC_RELAXED, __HIP_MEMORY_SCOPE_AGENT);
      // hout + next gx prefetch hidden under the poll
#pragma unroll
      for (int r = 0; r < 4; r++)
        h[((size_t)(rowbase + r) * NT + (t0 + t)) * NH + j] = hhi_s[r];
#pragma unroll
      for (int r = 0; r < 4; r++) {
        const f16* gp = gx + ((size_t)(rowbase + r) * Tc + (t + 1)) * NG + j;
        xr[r] = (float)gp[0]; xz[r] = (float)gp[NH]; xn[r] = (float)gp[2 * NH];
      }
      asm volatile("" ::: "memory");
      const u32 target = (u32)(bar_base + t + 1);
      for (;;) {
        u32 v = __hip_atomic_load(gflags + lane,
                                  __ATOMIC_RELAXED, __HIP_MEMORY_SCOPE_AGENT);
        if (__all(v >= target)) break;
        __builtin_amdgcn_s_sleep(1);
      }
      asm volatile("" ::: "memory");
    } else {
#pragma unroll
      for (int r = 0; r < 4; r++)
        h[((size_t)(rowbase + r) * NT + (t0 + t)) * NH + j] = hhi_s[r];
    }
    cur ^= 1;
  }
}

// ---- final FC
__global__ void k_fc(const f16* __restrict__ h, const float* __restrict__ fcw,
                     const float* __restrict__ fcb, float* __restrict__ out) {
  int b = blockIdx.x;
  int lane = threadIdx.x;  // 64
  __shared__ float hrow[NH];
  for (int k = lane; k < NH; k += 64)
    hrow[k] = (float)h[((size_t)b * NT + (NT - 1)) * NH + k];
  __syncthreads();
  for (int o = 0; o < NOUT; o++) {
    float sm = 0.f;
    for (int k = lane; k < NH; k += 64) sm += hrow[k] * fcw[o * NH + k];
#pragma unroll
    for (int off = 32; off; off >>= 1) sm += __shfl_down(sm, off);
    if (lane == 0) out[b * NOUT + o] = sm + fcb[o];
  }
}

extern "C" void kernel_launch(void* const* d_in, const int* in_sizes, int n_in,
                              void* d_out, int out_size, void* d_ws, size_t ws_size,
                              hipStream_t stream) {
  (void)in_sizes; (void)n_in; (void)out_size;
  const float* x = (const float*)d_in[0];
  const float* w_ih[3] = {(const float*)d_in[1], (const float*)d_in[5], (const float*)d_in[9]};
  const float* w_hh[3] = {(const float*)d_in[2], (const float*)d_in[6], (const float*)d_in[10]};
  const float* b_ih[3] = {(const float*)d_in[3], (const float*)d_in[7], (const float*)d_in[11]};
  const float* b_hh[3] = {(const float*)d_in[4], (const float*)d_in[8], (const float*)d_in[12]};
  const float* fcw = (const float*)d_in[13];
  const float* fcb = (const float*)d_in[14];

  const size_t fixed = 32768 +
                       ((size_t)NG * ND + 2 * (size_t)NG * NH) * 2 /*wih*/ +
                       3 * (size_t)NG * NH * 2 /*whh*/ +
                       (size_t)NB * NT * ND * 2 /*xf16*/ +
                       (size_t)NB * NT * NH * 2 /*h*/ +
                       3 * (size_t)2 * PL * 4 /*exq*/;
  int Tc = 64;  // 3 gx buffers must fit
  while (Tc > 16 && fixed + 3 * ((size_t)NB * Tc * NG * 2) > ws_size) Tc >>= 1;
  const int nc = NT / Tc;
  int tsh = 0;
  while ((1 << tsh) < Tc) tsh++;

  char* p = (char*)d_ws;
  size_t off = 0;
  u32* ctrl = (u32*)(p + off); off += 32768;  // 3 layers x 8 groups x 64 wave-flags
  f16* wih_f[3]; f16* whh_f[3];
  const int wih_sz[3] = {NG * ND, NG * NH, NG * NH};
  for (int l = 0; l < 3; l++) {
    wih_f[l] = (f16*)(p + off); off += (size_t)wih_sz[l] * 2;
    whh_f[l] = (f16*)(p + off); off += (size_t)NG * NH * 2;
  }
  f16* xf16 = (f16*)(p + off); off += (size_t)NB * NT * ND * 2;
  f16* h = (f16*)(p + off); off += (size_t)NB * NT * NH * 2;
  u32* exq[3];
  for (int l = 0; l < 3; l++) {
    exq[l] = (u32*)(p + off); off += (size_t)2 * PL * 4;
  }
  f16* gxbuf[3];
  for (int s = 0; s < 3; s++) {
    gxbuf[s] = (f16*)(p + off); off += (size_t)NB * Tc * NG * 2;
  }

  hipMemsetAsync(ctrl, 0, 32768, stream);

  auto conv = [&](const float* src, f16* dst, int n) {
    int blocks = (n + 1023) / 1024; if (blocks > 2048) blocks = 2048;
    k_f32_to_f16<<<dim3(blocks), dim3(256), 0, stream>>>(src, dst, n);
  };
  conv(x, xf16, NB * NT * ND);
  for (int l = 0; l < 3; l++) {
    conv(w_ih[l], wih_f[l], wih_sz[l]);
    conv(w_hh[l], whh_f[l], NG * NH);
  }

  const int mblocks = (NB * Tc) / 128;  // grid.y = NG/128 = 12

  // ---- anti-diagonal wavefront: diagonal d = {(l, d-l)}; <=3 units/launch ----
  for (int d = 0; d < 3 + nc - 1; d++) {
    int pl_[3], pc_[3], np = 0;
    for (int l = 0; l < 3; l++) {
      int c = d - l;
      if (c < 0 || c >= nc) continue;
      pl_[np] = l; pc_[np] = c; np++;
    }
    if (np == 0) continue;
    for (int s = 0; s < np; s++) {
      int l = pl_[s], c = pc_[s];
      if (l == 0)
        k_gemm2<ND><<<dim3(mblocks, 12), dim3(256), 0, stream>>>(
            xf16, wih_f[0], b_ih[0], gxbuf[s], c * Tc, tsh);
      else
        k_gemm2<NH><<<dim3(mblocks, 12), dim3(256), 0, stream>>>(
            h, wih_f[l], b_ih[l], gxbuf[s], c * Tc, tsh);
    }
    RecUnit us[3];
    for (int s = 0; s < np; s++) {
      int l = pl_[s], c = pc_[s];
      us[s].gx = gxbuf[s];
      us[s].whh = whh_f[l];
      us[s].bhh = b_hh[l];
      us[s].exq = exq[l];
      us[s].fl = ctrl + l * 512;
      us[s].t0 = c * Tc;
      us[s].bar_base = c * (Tc - 1);
    }
    for (int s = np; s < 3; s++) us[s] = us[0];
    k_rec<<<dim3(np * 128), dim3(256), 0, stream>>>(us[0], us[1], us[2], h, Tc);
  }
  k_fc<<<dim3(NB), dim3(64), 0, stream>>>(h, fcw, fcb, (float*)d_out);
}

// Round 17
// 2646.113 us; speedup vs baseline: 1.1358x; 1.1358x over previous
//
#include <hip/hip_runtime.h>
#include <cstdint>
#include <cstddef>

typedef _Float16 f16;
typedef _Float16 f16x4 __attribute__((ext_vector_type(4)));
typedef _Float16 f16x8 __attribute__((ext_vector_type(8)));
typedef float f32x4 __attribute__((ext_vector_type(4)));
typedef unsigned int u32;
typedef unsigned short u16;
typedef u32 u32x4 __attribute__((ext_vector_type(4)));

#define NB 256
#define NT 256
#define ND 128
#define NH 512
#define NG 1536
#define NOUT 24
#define PL (NB * NH)  // one packed exchange plane (u32 elements)

__device__ __forceinline__ float fsig(float x) {
  float e = __expf(-x);
  return __fdividef(1.0f, 1.0f + e);
}
__device__ __forceinline__ float ftanh(float x) {
  float ax = __builtin_fabsf(x);
  float e = __expf(-2.0f * ax);
  float t = __fdividef(1.0f - e, 1.0f + e);
  return __builtin_copysignf(t, x);
}

// ---- all f32->f16 conversions in ONE dispatch (7 segments) ----
__global__ void k_conv_all(
    const float* s0, f16* d0, int n0, const float* s1, f16* d1, int n1,
    const float* s2, f16* d2, int n2, const float* s3, f16* d3, int n3,
    const float* s4, f16* d4, int n4, const float* s5, f16* d5, int n5,
    const float* s6, f16* d6, int n6) {
  const int stride = gridDim.x * blockDim.x;
  const int t = blockIdx.x * blockDim.x + threadIdx.x;
#define CONVSEG(S, D, N)                                        \
  for (int i = t; i < (N) / 4; i += stride) {                   \
    float4 v = *(const float4*)((S) + (size_t)i * 4);           \
    f16x4 o = {(f16)v.x, (f16)v.y, (f16)v.z, (f16)v.w};        \
    *(f16x4*)((D) + (size_t)i * 4) = o;                         \
  }
  CONVSEG(s0, d0, n0)
  CONVSEG(s1, d1, n1)
  CONVSEG(s2, d2, n2)
  CONVSEG(s3, d3, n3)
  CONVSEG(s4, d4, n4)
  CONVSEG(s5, d5, n5)
  CONVSEG(s6, d6, n6)
#undef CONVSEG
}

// async global->LDS, 16B per lane (dest = wave-uniform base + lane*16)
__device__ __forceinline__ void gl16(const f16* g, f16* l) {
  __builtin_amdgcn_global_load_lds(
      (const __attribute__((address_space(1))) u32*)(const void*)g,
      (__attribute__((address_space(3))) u32*)(void*)l, 16, 0, 0);
}

// ---- gx GEMM, BK=64: gx = A @ W^T + b. BM=BN=128, 256 thr (2x2 waves).
// 8 K-iterations (vs 16 at BK=32): half the stage-drain-barrier pairs.
// LDS [128][64] per tile; row chunk swizzle c' = c ^ (row&7): source is
// pre-swizzled, read applies the same xor (both-sides rule), 2-way banks.
template <int K>
__global__ __launch_bounds__(256) void k_gemm2(
    const f16* __restrict__ A, const f16* __restrict__ W,
    const float* __restrict__ bias, f16* __restrict__ gx, int t0, int tsh) {
  __shared__ f16 As[128 * 64];
  __shared__ f16 Bs[128 * 64];
  const int tid = threadIdx.x;
  const int wave = tid >> 6, lane = tid & 63;
  const int wm = wave >> 1, wn = wave & 1;
  const int m0 = blockIdx.x * 128;
  const int n0 = blockIdx.y * 128;
  const int tmask = (1 << tsh) - 1;

  // staging: thread -> rows r0+{0,32,64,96}, dest chunk tid&7 (linear),
  // source chunk (tid&7)^(r0&7) — pre-swizzle on the global address.
  const int r0 = tid >> 3;
  const int csrc = ((tid & 7) ^ (r0 & 7)) * 8;
  const f16* ap[4];
  const f16* bp[4];
#pragma unroll
  for (int q = 0; q < 4; q++) {
    int ga = m0 + r0 + q * 32;
    int gr = ((ga >> tsh) << 8) + t0 + (ga & tmask);
    ap[q] = A + (size_t)gr * K + csrc;
    bp[q] = W + (size_t)(n0 + r0 + q * 32) * K + csrc;
  }
  f16* asw = As + wave * 512;  // wave-uniform bases (512 f16 = 1KB per wave)
  f16* bsw = Bs + wave * 512;

  const int lr = lane & 15;
  const int kg = lane >> 4;
  const int sw = lr & 7;  // read-side xor; row&7 == lr&7 for all frag rows

  f32x4 acc[4][4];
#pragma unroll
  for (int i = 0; i < 4; i++)
#pragma unroll
    for (int j = 0; j < 4; j++) acc[i][j] = (f32x4){0.f, 0.f, 0.f, 0.f};

  for (int k0 = 0; k0 < K; k0 += 64) {
#pragma unroll
    for (int q = 0; q < 4; q++) {
      gl16(ap[q] + k0, asw + q * 2048);
      gl16(bp[q] + k0, bsw + q * 2048);
    }
    asm volatile("s_waitcnt vmcnt(0)" ::: "memory");
    __syncthreads();
#pragma unroll
    for (int s = 0; s < 2; s++) {
      const int koff = ((s * 4 + kg) ^ sw) * 8;
      f16x8 af[4], bf[4];
#pragma unroll
      for (int i = 0; i < 4; i++)
        af[i] = *(const f16x8*)(As + (wm * 64 + i * 16 + lr) * 64 + koff);
#pragma unroll
      for (int j = 0; j < 4; j++)
        bf[j] = *(const f16x8*)(Bs + (wn * 64 + j * 16 + lr) * 64 + koff);
#pragma unroll
      for (int i = 0; i < 4; i++)
#pragma unroll
        for (int j = 0; j < 4; j++)
          acc[i][j] = __builtin_amdgcn_mfma_f32_16x16x32_f16(af[i], bf[j], acc[i][j], 0, 0, 0);
    }
    __syncthreads();
  }
  const int rowb = (lane >> 4) * 4;
#pragma unroll
  for (int j = 0; j < 4; j++) {
    int col = n0 + wn * 64 + j * 16 + lr;
    float bv = bias[col];
#pragma unroll
    for (int i = 0; i < 4; i++) {
      int row = m0 + wm * 64 + i * 16 + rowb;
#pragma unroll
      for (int rr = 0; rr < 4; rr++)
        gx[(size_t)(row + rr) * NG + col] = (f16)(acc[i][j][rr] + bv);
    }
  }
}

// issue one 4-kk batch (8 dwordx4, system-coherent) from packed plane
#define ISSUE4K(qarr, kkb)                                               \
  _Pragma("unroll") for (int u_ = 0; u_ < 4; u_++) {                     \
    const u32* pp_ = hq + (kkb + u_) * 32 + lkh * 8;                     \
    asm volatile("global_load_dwordx4 %0, %1, off sc0 sc1"               \
                 : "=v"(qarr[2 * u_]) : "v"(pp_));                       \
    asm volatile("global_load_dwordx4 %0, %1, off sc0 sc1"               \
                 : "=v"(qarr[2 * u_ + 1]) : "v"(pp_ + 4));               \
  }

// consume one 4-kk batch: unpack hi/lo, 12 MFMA per kk. n-gate B-frags come
// from registers (bnO/bnX, statically indexed by nb0+u_); r,z from LDS.
#define CONS4K(qarr, kkb, nb0)                                                       \
  _Pragma("unroll") for (int u_ = 0; u_ < 4; u_++) {                                 \
    const int kk_ = kkb + u_;                                                        \
    union { u32 w[4]; f16x8 v; } AH_, AL_;                                           \
    AH_.w[0] = __builtin_amdgcn_perm(qarr[2*u_][1],   qarr[2*u_][0],   0x05040100u); \
    AH_.w[1] = __builtin_amdgcn_perm(qarr[2*u_][3],   qarr[2*u_][2],   0x05040100u); \
    AH_.w[2] = __builtin_amdgcn_perm(qarr[2*u_+1][1], qarr[2*u_+1][0], 0x05040100u); \
    AH_.w[3] = __builtin_amdgcn_perm(qarr[2*u_+1][3], qarr[2*u_+1][2], 0x05040100u); \
    AL_.w[0] = __builtin_amdgcn_perm(qarr[2*u_][1],   qarr[2*u_][0],   0x07060302u); \
    AL_.w[1] = __builtin_amdgcn_perm(qarr[2*u_][3],   qarr[2*u_][2],   0x07060302u); \
    AL_.w[2] = __builtin_amdgcn_perm(qarr[2*u_+1][1], qarr[2*u_+1][0], 0x07060302u); \
    AL_.w[3] = __builtin_amdgcn_perm(qarr[2*u_+1][3], qarr[2*u_+1][2], 0x07060302u); \
    const int co_ = (((kk_ * 4 + lkh) ^ swz) << 3);                                  \
    f16x8 bro_ = *(const f16x8*)(wro_ + co_);                                        \
    f16x8 bzo_ = *(const f16x8*)(wzo_ + co_);                                        \
    f16x8 brx_ = *(const f16x8*)(wrx_ + co_);                                        \
    f16x8 bzx_ = *(const f16x8*)(wzx_ + co_);                                        \
    f16x8 bno_ = bnO[nb0 + u_];                                                      \
    f16x8 bnx_ = bnX[nb0 + u_];                                                      \
    aRo = __builtin_amdgcn_mfma_f32_16x16x32_f16(AH_.v, bro_, aRo, 0, 0, 0);         \
    aZo = __builtin_amdgcn_mfma_f32_16x16x32_f16(AH_.v, bzo_, aZo, 0, 0, 0);         \
    aNo = __builtin_amdgcn_mfma_f32_16x16x32_f16(AH_.v, bno_, aNo, 0, 0, 0);         \
    aRx = __builtin_amdgcn_mfma_f32_16x16x32_f16(AH_.v, brx_, aRx, 0, 0, 0);         \
    aZx = __builtin_amdgcn_mfma_f32_16x16x32_f16(AH_.v, bzx_, aZx, 0, 0, 0);         \
    aNx = __builtin_amdgcn_mfma_f32_16x16x32_f16(AH_.v, bnx_, aNx, 0, 0, 0);         \
    aRo = __builtin_amdgcn_mfma_f32_16x16x32_f16(AL_.v, bro_, aRo, 0, 0, 0);         \
    aZo = __builtin_amdgcn_mfma_f32_16x16x32_f16(AL_.v, bzo_, aZo, 0, 0, 0);         \
    aNo = __builtin_amdgcn_mfma_f32_16x16x32_f16(AL_.v, bno_, aNo, 0, 0, 0);         \
    aRx = __builtin_amdgcn_mfma_f32_16x16x32_f16(AL_.v, brx_, aRx, 0, 0, 0);         \
    aZx = __builtin_amdgcn_mfma_f32_16x16x32_f16(AL_.v, bzx_, aZx, 0, 0, 0);         \
    aNx = __builtin_amdgcn_mfma_f32_16x16x32_f16(AL_.v, bnx_, aNx, 0, 0, 0);         \
  }

struct RecUnit {
  const f16* gx; const f16* whh; const float* bhh;
  u32* exq; u32* fl; int t0; int bar_base;
};

// ---- GRU recurrence (r12 core; proven at 2.556 ms). <=3 independent 128-block
// units per launch. n-gate weights register-resident; r,z in LDS (64KB,
// swizzled) -> 77KB LDS -> 2 blocks/CU -> 384 blocks co-resident with slack.
// Tail: block drain + one flag/block on one 64B line/group (the bracketed
// local optimum of the sync design space).
__global__ __launch_bounds__(256, 2) void k_rec(
    RecUnit u0, RecUnit u1, RecUnit u2, f16* __restrict__ h, int Tc) {
  __shared__ f16 wlds[64 * 512];
  __shared__ float plds[2][2][64][12];
  RecUnit U = u0;
  const int ui = blockIdx.x >> 7;
  if (ui == 1) U = u1;
  if (ui == 2) U = u2;
  const int bid = blockIdx.x & 127;
  const f16* __restrict__ gx = U.gx;
  u32* __restrict__ exq = U.exq;
  const int t0 = U.t0, bar_base = U.bar_base;
  const int tid = threadIdx.x;
  const int g = bid >> 4;
  const int cs = bid & 15;
  const int b0 = g * 32, c0 = cs * 32;
  const int lane = tid & 63, wave = tid >> 6;
  const int wm = wave >> 1, ks = wave & 1;
  const int lr = lane & 15, lkh = lane >> 4;
  const int first = (t0 == 0) ? 1 : 0;
  const int jo = ks * 16 + lr;
  const int jx = (1 - ks) * 16 + lr;
  const int ks8 = ks * 8;

  // n-gate weights -> registers (issue first; overlaps LDS staging)
  f16x8 bnO[8], bnX[8];
  {
    const f16* wb = U.whh + (size_t)(2 * NH + c0) * NH + (size_t)ks8 * 32 + lkh * 8;
    const f16* wO = wb + (size_t)jo * NH;
    const f16* wX = wb + (size_t)jx * NH;
#pragma unroll
    for (int i = 0; i < 8; i++) {
      bnO[i] = *(const f16x8*)(wO + i * 32);
      bnX[i] = *(const f16x8*)(wX + i * 32);
    }
  }
  // r,z gates -> LDS (swizzled 16B chunks)
  for (int idx = tid; idx < 64 * 64; idx += 256) {
    int lrw = idx >> 6, c = idx & 63;
    int grow = (lrw >> 5) * NH + c0 + (lrw & 31);
    f16x8 v = *(const f16x8*)(U.whh + (size_t)grow * NH + c * 8);
    *(f16x8*)(wlds + lrw * 512 + ((c ^ (lrw & 7)) << 3)) = v;
  }
  __syncthreads();

  const int j = c0 + jo;
  const float bh_r = U.bhh[j], bh_z = U.bhh[NH + j], bh_n = U.bhh[2 * NH + j];
  const int arow = b0 + wm * 16 + lr;
  const int rowbase = b0 + wm * 16 + lkh * 4;
  const int swz = lr & 7;
  const f16* wro_ = wlds + jo * 512;
  const f16* wzo_ = wlds + (32 + jo) * 512;
  const f16* wrx_ = wlds + jx * 512;
  const f16* wzx_ = wlds + (32 + jx) * 512;
  u32* myflag = U.fl + g * 64 + cs;
  u32* gflags = U.fl + g * 64;
  const int pl = lane & 15;

  union PK2 { u32 u; f16 hh[2]; };

  float hold[4];
  if (first) {
#pragma unroll
    for (int r = 0; r < 4; r++) hold[r] = 0.f;
  } else {
#pragma unroll
    for (int r = 0; r < 4; r++) {
      PK2 pk;
      pk.u = __hip_atomic_load(exq + (size_t)(rowbase + r) * NH + j,
                               __ATOMIC_RELAXED, __HIP_MEMORY_SCOPE_AGENT);
      hold[r] = (float)pk.hh[0] + (float)pk.hh[1];
    }
  }

  float xr[4], xz[4], xn[4];
#pragma unroll
  for (int r = 0; r < 4; r++) {
    const f16* gp = gx + ((size_t)(rowbase + r) * Tc) * NG + j;
    xr[r] = (float)gp[0]; xz[r] = (float)gp[NH]; xn[r] = (float)gp[2 * NH];
  }

  int cur = 0;
  for (int t = 0; t < Tc; t++) {
    f32x4 aRo = {0.f, 0.f, 0.f, 0.f}, aZo = {0.f, 0.f, 0.f, 0.f}, aNo = {0.f, 0.f, 0.f, 0.f};
    f32x4 aRx = {0.f, 0.f, 0.f, 0.f}, aZx = {0.f, 0.f, 0.f, 0.f}, aNx = {0.f, 0.f, 0.f, 0.f};
    if (t > 0 || !first) {
      const u32* hq = exq + (size_t)cur * PL + (size_t)arow * NH;
      u32x4 q0[8], q1[8];
      ISSUE4K(q0, ks8);
      ISSUE4K(q1, ks8 + 4);
      asm volatile("s_waitcnt vmcnt(8)" ::: "memory");
      __builtin_amdgcn_sched_barrier(0);
      CONS4K(q0, ks8, 0);
      asm volatile("s_waitcnt vmcnt(0)" ::: "memory");
      __builtin_amdgcn_sched_barrier(0);
      CONS4K(q1, ks8 + 4, 4);
      float* ps = &plds[wm][ks][lane][0];
#pragma unroll
      for (int i = 0; i < 4; i++) {
        ps[i] = aRx[i]; ps[4 + i] = aZx[i]; ps[8 + i] = aNx[i];
      }
      __syncthreads();
      const float* pr = &plds[wm][1 - ks][lane][0];
#pragma unroll
      for (int i = 0; i < 4; i++) {
        aRo[i] += pr[i]; aZo[i] += pr[4 + i]; aNo[i] += pr[8 + i];
      }
    }
    u32* outq = exq + (size_t)(cur ^ 1) * PL;
    f16 hhi_s[4];
#pragma unroll
    for (int r = 0; r < 4; r++) {
      float rg = fsig(xr[r] + aRo[r] + bh_r);
      float zg = fsig(xz[r] + aZo[r] + bh_z);
      float ng = ftanh(xn[r] + rg * (aNo[r] + bh_n));
      float hnew = ng + zg * (hold[r] - ng);
      hold[r] = hnew;
      PK2 pk;
      pk.hh[0] = (f16)hnew;
      pk.hh[1] = (f16)(hnew - (float)pk.hh[0]);
      hhi_s[r] = pk.hh[0];
      __hip_atomic_store(outq + (size_t)(rowbase + r) * NH + j, pk.u,
                         __ATOMIC_RELAXED, __HIP_MEMORY_SCOPE_AGENT);
    }
    if (t < Tc - 1) {
      asm volatile("s_waitcnt vmcnt(0)" ::: "memory");
      __syncthreads();
      if (tid == 0)
        __hip_atomic_store(myflag, (u32)(bar_base + t + 1),
                           __ATOMIC_RELAXED, __HIP_MEMORY_SCOPE_AGENT);
#pragma unroll
      for (int r = 0; r < 4; r++)
        h[((size_t)(rowbase + r) * NT + (t0 + t)) * NH + j] = hhi_s[r];
#pragma unroll
      for (int r = 0; r < 4; r++) {
        const f16* gp = gx + ((size_t)(rowbase + r) * Tc + (t + 1)) * NG + j;
        xr[r] = (float)gp[0]; xz[r] = (float)gp[NH]; xn[r] = (float)gp[2 * NH];
      }
      asm volatile("" ::: "memory");
      const u32 target = (u32)(bar_base + t + 1);
      for (;;) {
        u32 v = __hip_atomic_load(gflags + pl,
                                  __ATOMIC_RELAXED, __HIP_MEMORY_SCOPE_AGENT);
        if (__all(v >= target)) break;
        __builtin_amdgcn_s_sleep(1);
      }
      asm volatile("" ::: "memory");
    } else {
#pragma unroll
      for (int r = 0; r < 4; r++)
        h[((size_t)(rowbase + r) * NT + (t0 + t)) * NH + j] = hhi_s[r];
    }
    cur ^= 1;
  }
}

// ---- final FC
__global__ void k_fc(const f16* __restrict__ h, const float* __restrict__ fcw,
                     const float* __restrict__ fcb, float* __restrict__ out) {
  int b = blockIdx.x;
  int lane = threadIdx.x;  // 64
  __shared__ float hrow[NH];
  for (int k = lane; k < NH; k += 64)
    hrow[k] = (float)h[((size_t)b * NT + (NT - 1)) * NH + k];
  __syncthreads();
  for (int o = 0; o < NOUT; o++) {
    float sm = 0.f;
    for (int k = lane; k < NH; k += 64) sm += hrow[k] * fcw[o * NH + k];
#pragma unroll
    for (int off = 32; off; off >>= 1) sm += __shfl_down(sm, off);
    if (lane == 0) out[b * NOUT + o] = sm + fcb[o];
  }
}

extern "C" void kernel_launch(void* const* d_in, const int* in_sizes, int n_in,
                              void* d_out, int out_size, void* d_ws, size_t ws_size,
                              hipStream_t stream) {
  (void)in_sizes; (void)n_in; (void)out_size;
  const float* x = (const float*)d_in[0];
  const float* w_ih[3] = {(const float*)d_in[1], (const float*)d_in[5], (const float*)d_in[9]};
  const float* w_hh[3] = {(const float*)d_in[2], (const float*)d_in[6], (const float*)d_in[10]};
  const float* b_ih[3] = {(const float*)d_in[3], (const float*)d_in[7], (const float*)d_in[11]};
  const float* b_hh[3] = {(const float*)d_in[4], (const float*)d_in[8], (const float*)d_in[12]};
  const float* fcw = (const float*)d_in[13];
  const float* fcb = (const float*)d_in[14];

  const size_t fixed = 32768 +
                       ((size_t)NG * ND + 2 * (size_t)NG * NH) * 2 /*wih*/ +
                       3 * (size_t)NG * NH * 2 /*whh*/ +
                       (size_t)NB * NT * ND * 2 /*xf16*/ +
                       (size_t)NB * NT * NH * 2 /*h*/ +
                       3 * (size_t)2 * PL * 4 /*exq*/;
  int Tc = 64;  // 3 gx buffers must fit
  while (Tc > 16 && fixed + 3 * ((size_t)NB * Tc * NG * 2) > ws_size) Tc >>= 1;
  const int nc = NT / Tc;
  int tsh = 0;
  while ((1 << tsh) < Tc) tsh++;

  char* p = (char*)d_ws;
  size_t off = 0;
  u32* ctrl = (u32*)(p + off); off += 32768;  // 3 layers x 8 groups x 64B flag line
  f16* wih_f[3]; f16* whh_f[3];
  const int wih_sz[3] = {NG * ND, NG * NH, NG * NH};
  for (int l = 0; l < 3; l++) {
    wih_f[l] = (f16*)(p + off); off += (size_t)wih_sz[l] * 2;
    whh_f[l] = (f16*)(p + off); off += (size_t)NG * NH * 2;
  }
  f16* xf16 = (f16*)(p + off); off += (size_t)NB * NT * ND * 2;
  f16* h = (f16*)(p + off); off += (size_t)NB * NT * NH * 2;
  u32* exq[3];
  for (int l = 0; l < 3; l++) {
    exq[l] = (u32*)(p + off); off += (size_t)2 * PL * 4;
  }
  f16* gxbuf[3];
  for (int s = 0; s < 3; s++) {
    gxbuf[s] = (f16*)(p + off); off += (size_t)NB * Tc * NG * 2;
  }

  hipMemsetAsync(ctrl, 0, 32768, stream);

  // all conversions in one dispatch
  k_conv_all<<<dim3(2048), dim3(256), 0, stream>>>(
      x, xf16, NB * NT * ND,
      w_ih[0], wih_f[0], wih_sz[0], w_hh[0], whh_f[0], NG * NH,
      w_ih[1], wih_f[1], wih_sz[1], w_hh[1], whh_f[1], NG * NH,
      w_ih[2], wih_f[2], wih_sz[2], w_hh[2], whh_f[2], NG * NH);

  const int mblocks = (NB * Tc) / 128;  // grid.y = NG/128 = 12

  // ---- anti-diagonal wavefront: diagonal d = {(l, d-l)}; <=3 units/launch ----
  for (int d = 0; d < 3 + nc - 1; d++) {
    int pl_[3], pc_[3], np = 0;
    for (int l = 0; l < 3; l++) {
      int c = d - l;
      if (c < 0 || c >= nc) continue;
      pl_[np] = l; pc_[np] = c; np++;
    }
    if (np == 0) continue;
    for (int s = 0; s < np; s++) {
      int l = pl_[s], c = pc_[s];
      if (l == 0)
        k_gemm2<ND><<<dim3(mblocks, 12), dim3(256), 0, stream>>>(
            xf16, wih_f[0], b_ih[0], gxbuf[s], c * Tc, tsh);
      else
        k_gemm2<NH><<<dim3(mblocks, 12), dim3(256), 0, stream>>>(
            h, wih_f[l], b_ih[l], gxbuf[s], c * Tc, tsh);
    }
    RecUnit us[3];
    for (int s = 0; s < np; s++) {
      int l = pl_[s], c = pc_[s];
      us[s].gx = gxbuf[s];
      us[s].whh = whh_f[l];
      us[s].bhh = b_hh[l];
      us[s].exq = exq[l];
      us[s].fl = ctrl + l * 512;
      us[s].t0 = c * Tc;
      us[s].bar_base = c * (Tc - 1);
    }
    for (int s = np; s < 3; s++) us[s] = us[0];
    k_rec<<<dim3(np * 128), dim3(256), 0, stream>>>(us[0], us[1], us[2], h, Tc);
  }
  k_fc<<<dim3(NB), dim3(64), 0, stream>>>(h, fcw, fcb, (float*)d_out);
}

// Round 18
// 2553.226 us; speedup vs baseline: 1.1771x; 1.0364x over previous
//
#include <hip/hip_runtime.h>
#include <cstdint>
#include <cstddef>

typedef _Float16 f16;
typedef _Float16 f16x4 __attribute__((ext_vector_type(4)));
typedef _Float16 f16x8 __attribute__((ext_vector_type(8)));
typedef float f32x4 __attribute__((ext_vector_type(4)));
typedef unsigned int u32;
typedef unsigned short u16;
typedef u32 u32x4 __attribute__((ext_vector_type(4)));

#define NB 256
#define NT 256
#define ND 128
#define NH 512
#define NG 1536
#define NOUT 24
#define PL (NB * NH)  // one packed exchange plane (u32 elements)

__device__ __forceinline__ float fsig(float x) {
  float e = __expf(-x);
  return __fdividef(1.0f, 1.0f + e);
}
__device__ __forceinline__ float ftanh(float x) {
  float ax = __builtin_fabsf(x);
  float e = __expf(-2.0f * ax);
  float t = __fdividef(1.0f - e, 1.0f + e);
  return __builtin_copysignf(t, x);
}

// ---- all f32->f16 conversions in ONE dispatch (7 segments) ----
__global__ void k_conv_all(
    const float* s0, f16* d0, int n0, const float* s1, f16* d1, int n1,
    const float* s2, f16* d2, int n2, const float* s3, f16* d3, int n3,
    const float* s4, f16* d4, int n4, const float* s5, f16* d5, int n5,
    const float* s6, f16* d6, int n6) {
  const int stride = gridDim.x * blockDim.x;
  const int t = blockIdx.x * blockDim.x + threadIdx.x;
#define CONVSEG(S, D, N)                                        \
  for (int i = t; i < (N) / 4; i += stride) {                   \
    float4 v = *(const float4*)((S) + (size_t)i * 4);           \
    f16x4 o = {(f16)v.x, (f16)v.y, (f16)v.z, (f16)v.w};        \
    *(f16x4*)((D) + (size_t)i * 4) = o;                         \
  }
  CONVSEG(s0, d0, n0)
  CONVSEG(s1, d1, n1)
  CONVSEG(s2, d2, n2)
  CONVSEG(s3, d3, n3)
  CONVSEG(s4, d4, n4)
  CONVSEG(s5, d5, n5)
  CONVSEG(s6, d6, n6)
#undef CONVSEG
}

// async global->LDS, 16B per lane (dest = wave-uniform base + lane*16)
__device__ __forceinline__ void gl16(const f16* g, f16* l) {
  __builtin_amdgcn_global_load_lds(
      (const __attribute__((address_space(1))) u32*)(const void*)g,
      (__attribute__((address_space(3))) u32*)(void*)l, 16, 0, 0);
}

// ---- m97-style gx GEMM (proven r14/r15): gx = A @ W^T + b. BM=BN=128, BK=32.
template <int K>
__global__ __launch_bounds__(256) void k_gemm2(
    const f16* __restrict__ A, const f16* __restrict__ W,
    const float* __restrict__ bias, f16* __restrict__ gx, int t0, int tsh) {
  __shared__ f16 As[128 * 32];
  __shared__ f16 Bs[128 * 32];
  const int tid = threadIdx.x;
  const int wave = tid >> 6, lane = tid & 63;
  const int wm = wave >> 1, wn = wave & 1;
  const int m0 = blockIdx.x * 128;
  const int n0 = blockIdx.y * 128;
  const int tmask = (1 << tsh) - 1;

  const int r0 = tid >> 2;
  const int swzs = (r0 >> 1) & 3;
  const int csrc = ((tid & 3) ^ swzs) * 8;
  const int ga0 = m0 + r0, ga1 = m0 + r0 + 64;
  const int gr0 = ((ga0 >> tsh) << 8) + t0 + (ga0 & tmask);
  const int gr1 = ((ga1 >> tsh) << 8) + t0 + (ga1 & tmask);
  const f16* a0 = A + (size_t)gr0 * K + csrc;
  const f16* a1 = A + (size_t)gr1 * K + csrc;
  const f16* b0 = W + (size_t)(n0 + r0) * K + csrc;
  const f16* b1 = W + (size_t)(n0 + r0 + 64) * K + csrc;
  f16* asb = As + wave * 512;
  f16* bsb = Bs + wave * 512;

  const int lr = lane & 15;
  const int kg = lane >> 4;
  const int swzr = ((lr >> 1) & 3);
  const int koff = (kg ^ swzr) * 8;

  f32x4 acc[4][4];
#pragma unroll
  for (int i = 0; i < 4; i++)
#pragma unroll
    for (int j = 0; j < 4; j++) acc[i][j] = (f32x4){0.f, 0.f, 0.f, 0.f};

  for (int k0 = 0; k0 < K; k0 += 32) {
    gl16(a0 + k0, asb);
    gl16(a1 + k0, asb + 2048);
    gl16(b0 + k0, bsb);
    gl16(b1 + k0, bsb + 2048);
    asm volatile("s_waitcnt vmcnt(0)" ::: "memory");
    __syncthreads();
    f16x8 af[4], bf[4];
#pragma unroll
    for (int i = 0; i < 4; i++)
      af[i] = *(const f16x8*)(As + (wm * 64 + i * 16 + lr) * 32 + koff);
#pragma unroll
    for (int j = 0; j < 4; j++)
      bf[j] = *(const f16x8*)(Bs + (wn * 64 + j * 16 + lr) * 32 + koff);
#pragma unroll
    for (int i = 0; i < 4; i++)
#pragma unroll
      for (int j = 0; j < 4; j++)
        acc[i][j] = __builtin_amdgcn_mfma_f32_16x16x32_f16(af[i], bf[j], acc[i][j], 0, 0, 0);
    __syncthreads();
  }
  const int rowb = (lane >> 4) * 4;
#pragma unroll
  for (int j = 0; j < 4; j++) {
    int col = n0 + wn * 64 + j * 16 + lr;
    float bv = bias[col];
#pragma unroll
    for (int i = 0; i < 4; i++) {
      int row = m0 + wm * 64 + i * 16 + rowb;
#pragma unroll
      for (int rr = 0; rr < 4; rr++)
        gx[(size_t)(row + rr) * NG + col] = (f16)(acc[i][j][rr] + bv);
    }
  }
}

// issue one 4-kk batch (8 dwordx4, system-coherent) from packed plane
#define ISSUE4K(qarr, kkb)                                               \
  _Pragma("unroll") for (int u_ = 0; u_ < 4; u_++) {                     \
    const u32* pp_ = hq + (kkb + u_) * 32 + lkh * 8;                     \
    asm volatile("global_load_dwordx4 %0, %1, off sc0 sc1"               \
                 : "=v"(qarr[2 * u_]) : "v"(pp_));                       \
    asm volatile("global_load_dwordx4 %0, %1, off sc0 sc1"               \
                 : "=v"(qarr[2 * u_ + 1]) : "v"(pp_ + 4));               \
  }

// consume one 4-kk batch: unpack hi/lo, 12 MFMA per kk. n-gate B-frags come
// from registers (bnO/bnX, statically indexed by nb0+u_); r,z from LDS.
#define CONS4K(qarr, kkb, nb0)                                                       \
  _Pragma("unroll") for (int u_ = 0; u_ < 4; u_++) {                                 \
    const int kk_ = kkb + u_;                                                        \
    union { u32 w[4]; f16x8 v; } AH_, AL_;                                           \
    AH_.w[0] = __builtin_amdgcn_perm(qarr[2*u_][1],   qarr[2*u_][0],   0x05040100u); \
    AH_.w[1] = __builtin_amdgcn_perm(qarr[2*u_][3],   qarr[2*u_][2],   0x05040100u); \
    AH_.w[2] = __builtin_amdgcn_perm(qarr[2*u_+1][1], qarr[2*u_+1][0], 0x05040100u); \
    AH_.w[3] = __builtin_amdgcn_perm(qarr[2*u_+1][3], qarr[2*u_+1][2], 0x05040100u); \
    AL_.w[0] = __builtin_amdgcn_perm(qarr[2*u_][1],   qarr[2*u_][0],   0x07060302u); \
    AL_.w[1] = __builtin_amdgcn_perm(qarr[2*u_][3],   qarr[2*u_][2],   0x07060302u); \
    AL_.w[2] = __builtin_amdgcn_perm(qarr[2*u_+1][1], qarr[2*u_+1][0], 0x07060302u); \
    AL_.w[3] = __builtin_amdgcn_perm(qarr[2*u_+1][3], qarr[2*u_+1][2], 0x07060302u); \
    const int co_ = (((kk_ * 4 + lkh) ^ swz) << 3);                                  \
    f16x8 bro_ = *(const f16x8*)(wro_ + co_);                                        \
    f16x8 bzo_ = *(const f16x8*)(wzo_ + co_);                                        \
    f16x8 brx_ = *(const f16x8*)(wrx_ + co_);                                        \
    f16x8 bzx_ = *(const f16x8*)(wzx_ + co_);                                        \
    f16x8 bno_ = bnO[nb0 + u_];                                                      \
    f16x8 bnx_ = bnX[nb0 + u_];                                                      \
    aRo = __builtin_amdgcn_mfma_f32_16x16x32_f16(AH_.v, bro_, aRo, 0, 0, 0);         \
    aZo = __builtin_amdgcn_mfma_f32_16x16x32_f16(AH_.v, bzo_, aZo, 0, 0, 0);         \
    aNo = __builtin_amdgcn_mfma_f32_16x16x32_f16(AH_.v, bno_, aNo, 0, 0, 0);         \
    aRx = __builtin_amdgcn_mfma_f32_16x16x32_f16(AH_.v, brx_, aRx, 0, 0, 0);         \
    aZx = __builtin_amdgcn_mfma_f32_16x16x32_f16(AH_.v, bzx_, aZx, 0, 0, 0);         \
    aNx = __builtin_amdgcn_mfma_f32_16x16x32_f16(AH_.v, bnx_, aNx, 0, 0, 0);         \
    aRo = __builtin_amdgcn_mfma_f32_16x16x32_f16(AL_.v, bro_, aRo, 0, 0, 0);         \
    aZo = __builtin_amdgcn_mfma_f32_16x16x32_f16(AL_.v, bzo_, aZo, 0, 0, 0);         \
    aNo = __builtin_amdgcn_mfma_f32_16x16x32_f16(AL_.v, bno_, aNo, 0, 0, 0);         \
    aRx = __builtin_amdgcn_mfma_f32_16x16x32_f16(AL_.v, brx_, aRx, 0, 0, 0);         \
    aZx = __builtin_amdgcn_mfma_f32_16x16x32_f16(AL_.v, bzx_, aZx, 0, 0, 0);         \
    aNx = __builtin_amdgcn_mfma_f32_16x16x32_f16(AL_.v, bnx_, aNx, 0, 0, 0);         \
  }

struct RecUnit {
  const f16* gx; const f16* whh; const float* bhh;
  u32* exq; u32* fl; int t0; int bar_base;
};

// ---- GRU recurrence (the 2.556-ms configuration, unchanged). <=3 independent
// 128-block units per launch. n-gate weights register-resident; r,z in LDS
// (64KB, swizzled) -> 77KB LDS -> 2 blocks/CU -> 384 blocks co-resident.
// Tail: block drain + one flag/block on one 64B line/group.
__global__ __launch_bounds__(256, 2) void k_rec(
    RecUnit u0, RecUnit u1, RecUnit u2, f16* __restrict__ h, int Tc) {
  __shared__ f16 wlds[64 * 512];
  __shared__ float plds[2][2][64][12];
  RecUnit U = u0;
  const int ui = blockIdx.x >> 7;
  if (ui == 1) U = u1;
  if (ui == 2) U = u2;
  const int bid = blockIdx.x & 127;
  const f16* __restrict__ gx = U.gx;
  u32* __restrict__ exq = U.exq;
  const int t0 = U.t0, bar_base = U.bar_base;
  const int tid = threadIdx.x;
  const int g = bid >> 4;
  const int cs = bid & 15;
  const int b0 = g * 32, c0 = cs * 32;
  const int lane = tid & 63, wave = tid >> 6;
  const int wm = wave >> 1, ks = wave & 1;
  const int lr = lane & 15, lkh = lane >> 4;
  const int first = (t0 == 0) ? 1 : 0;
  const int jo = ks * 16 + lr;
  const int jx = (1 - ks) * 16 + lr;
  const int ks8 = ks * 8;

  // n-gate weights -> registers (issue first; overlaps LDS staging)
  f16x8 bnO[8], bnX[8];
  {
    const f16* wb = U.whh + (size_t)(2 * NH + c0) * NH + (size_t)ks8 * 32 + lkh * 8;
    const f16* wO = wb + (size_t)jo * NH;
    const f16* wX = wb + (size_t)jx * NH;
#pragma unroll
    for (int i = 0; i < 8; i++) {
      bnO[i] = *(const f16x8*)(wO + i * 32);
      bnX[i] = *(const f16x8*)(wX + i * 32);
    }
  }
  // r,z gates -> LDS (swizzled 16B chunks)
  for (int idx = tid; idx < 64 * 64; idx += 256) {
    int lrw = idx >> 6, c = idx & 63;
    int grow = (lrw >> 5) * NH + c0 + (lrw & 31);
    f16x8 v = *(const f16x8*)(U.whh + (size_t)grow * NH + c * 8);
    *(f16x8*)(wlds + lrw * 512 + ((c ^ (lrw & 7)) << 3)) = v;
  }
  __syncthreads();

  const int j = c0 + jo;
  const float bh_r = U.bhh[j], bh_z = U.bhh[NH + j], bh_n = U.bhh[2 * NH + j];
  const int arow = b0 + wm * 16 + lr;
  const int rowbase = b0 + wm * 16 + lkh * 4;
  const int swz = lr & 7;
  const f16* wro_ = wlds + jo * 512;
  const f16* wzo_ = wlds + (32 + jo) * 512;
  const f16* wrx_ = wlds + jx * 512;
  const f16* wzx_ = wlds + (32 + jx) * 512;
  u32* myflag = U.fl + g * 64 + cs;
  u32* gflags = U.fl + g * 64;
  const int pl = lane & 15;

  union PK2 { u32 u; f16 hh[2]; };

  float hold[4];
  if (first) {
#pragma unroll
    for (int r = 0; r < 4; r++) hold[r] = 0.f;
  } else {
#pragma unroll
    for (int r = 0; r < 4; r++) {
      PK2 pk;
      pk.u = __hip_atomic_load(exq + (size_t)(rowbase + r) * NH + j,
                               __ATOMIC_RELAXED, __HIP_MEMORY_SCOPE_AGENT);
      hold[r] = (float)pk.hh[0] + (float)pk.hh[1];
    }
  }

  float xr[4], xz[4], xn[4];
#pragma unroll
  for (int r = 0; r < 4; r++) {
    const f16* gp = gx + ((size_t)(rowbase + r) * Tc) * NG + j;
    xr[r] = (float)gp[0]; xz[r] = (float)gp[NH]; xn[r] = (float)gp[2 * NH];
  }

  int cur = 0;
  for (int t = 0; t < Tc; t++) {
    f32x4 aRo = {0.f, 0.f, 0.f, 0.f}, aZo = {0.f, 0.f, 0.f, 0.f}, aNo = {0.f, 0.f, 0.f, 0.f};
    f32x4 aRx = {0.f, 0.f, 0.f, 0.f}, aZx = {0.f, 0.f, 0.f, 0.f}, aNx = {0.f, 0.f, 0.f, 0.f};
    if (t > 0 || !first) {
      const u32* hq = exq + (size_t)cur * PL + (size_t)arow * NH;
      u32x4 q0[8], q1[8];
      ISSUE4K(q0, ks8);
      ISSUE4K(q1, ks8 + 4);
      asm volatile("s_waitcnt vmcnt(8)" ::: "memory");
      __builtin_amdgcn_sched_barrier(0);
      CONS4K(q0, ks8, 0);
      asm volatile("s_waitcnt vmcnt(0)" ::: "memory");
      __builtin_amdgcn_sched_barrier(0);
      CONS4K(q1, ks8 + 4, 4);
      float* ps = &plds[wm][ks][lane][0];
#pragma unroll
      for (int i = 0; i < 4; i++) {
        ps[i] = aRx[i]; ps[4 + i] = aZx[i]; ps[8 + i] = aNx[i];
      }
      __syncthreads();
      const float* pr = &plds[wm][1 - ks][lane][0];
#pragma unroll
      for (int i = 0; i < 4; i++) {
        aRo[i] += pr[i]; aZo[i] += pr[4 + i]; aNo[i] += pr[8 + i];
      }
    }
    u32* outq = exq + (size_t)(cur ^ 1) * PL;
    f16 hhi_s[4];
#pragma unroll
    for (int r = 0; r < 4; r++) {
      float rg = fsig(xr[r] + aRo[r] + bh_r);
      float zg = fsig(xz[r] + aZo[r] + bh_z);
      float ng = ftanh(xn[r] + rg * (aNo[r] + bh_n));
      float hnew = ng + zg * (hold[r] - ng);
      hold[r] = hnew;
      PK2 pk;
      pk.hh[0] = (f16)hnew;
      pk.hh[1] = (f16)(hnew - (float)pk.hh[0]);
      hhi_s[r] = pk.hh[0];
      __hip_atomic_store(outq + (size_t)(rowbase + r) * NH + j, pk.u,
                         __ATOMIC_RELAXED, __HIP_MEMORY_SCOPE_AGENT);
    }
    if (t < Tc - 1) {
      asm volatile("s_waitcnt vmcnt(0)" ::: "memory");
      __syncthreads();
      if (tid == 0)
        __hip_atomic_store(myflag, (u32)(bar_base + t + 1),
                           __ATOMIC_RELAXED, __HIP_MEMORY_SCOPE_AGENT);
#pragma unroll
      for (int r = 0; r < 4; r++)
        h[((size_t)(rowbase + r) * NT + (t0 + t)) * NH + j] = hhi_s[r];
#pragma unroll
      for (int r = 0; r < 4; r++) {
        const f16* gp = gx + ((size_t)(rowbase + r) * Tc + (t + 1)) * NG + j;
        xr[r] = (float)gp[0]; xz[r] = (float)gp[NH]; xn[r] = (float)gp[2 * NH];
      }
      asm volatile("" ::: "memory");
      const u32 target = (u32)(bar_base + t + 1);
      for (;;) {
        u32 v = __hip_atomic_load(gflags + pl,
                                  __ATOMIC_RELAXED, __HIP_MEMORY_SCOPE_AGENT);
        if (__all(v >= target)) break;
        __builtin_amdgcn_s_sleep(1);
      }
      asm volatile("" ::: "memory");
    } else {
#pragma unroll
      for (int r = 0; r < 4; r++)
        h[((size_t)(rowbase + r) * NT + (t0 + t)) * NH + j] = hhi_s[r];
    }
    cur ^= 1;
  }
}

// ---- final FC
__global__ void k_fc(const f16* __restrict__ h, const float* __restrict__ fcw,
                     const float* __restrict__ fcb, float* __restrict__ out) {
  int b = blockIdx.x;
  int lane = threadIdx.x;  // 64
  __shared__ float hrow[NH];
  for (int k = lane; k < NH; k += 64)
    hrow[k] = (float)h[((size_t)b * NT + (NT - 1)) * NH + k];
  __syncthreads();
  for (int o = 0; o < NOUT; o++) {
    float sm = 0.f;
    for (int k = lane; k < NH; k += 64) sm += hrow[k] * fcw[o * NH + k];
#pragma unroll
    for (int off = 32; off; off >>= 1) sm += __shfl_down(sm, off);
    if (lane == 0) out[b * NOUT + o] = sm + fcb[o];
  }
}

extern "C" void kernel_launch(void* const* d_in, const int* in_sizes, int n_in,
                              void* d_out, int out_size, void* d_ws, size_t ws_size,
                              hipStream_t stream) {
  (void)in_sizes; (void)n_in; (void)out_size;
  const float* x = (const float*)d_in[0];
  const float* w_ih[3] = {(const float*)d_in[1], (const float*)d_in[5], (const float*)d_in[9]};
  const float* w_hh[3] = {(const float*)d_in[2], (const float*)d_in[6], (const float*)d_in[10]};
  const float* b_ih[3] = {(const float*)d_in[3], (const float*)d_in[7], (const float*)d_in[11]};
  const float* b_hh[3] = {(const float*)d_in[4], (const float*)d_in[8], (const float*)d_in[12]};
  const float* fcw = (const float*)d_in[13];
  const float* fcb = (const float*)d_in[14];

  const size_t fixed = 32768 +
                       ((size_t)NG * ND + 2 * (size_t)NG * NH) * 2 /*wih*/ +
                       3 * (size_t)NG * NH * 2 /*whh*/ +
                       (size_t)NB * NT * ND * 2 /*xf16*/ +
                       (size_t)NB * NT * NH * 2 /*h*/ +
                       3 * (size_t)2 * PL * 4 /*exq*/;
  int Tc = 64;  // 3 gx buffers must fit
  while (Tc > 16 && fixed + 3 * ((size_t)NB * Tc * NG * 2) > ws_size) Tc >>= 1;
  const int nc = NT / Tc;
  int tsh = 0;
  while ((1 << tsh) < Tc) tsh++;

  char* p = (char*)d_ws;
  size_t off = 0;
  u32* ctrl = (u32*)(p + off); off += 32768;  // 3 layers x 8 groups x 64B flag line
  f16* wih_f[3]; f16* whh_f[3];
  const int wih_sz[3] = {NG * ND, NG * NH, NG * NH};
  for (int l = 0; l < 3; l++) {
    wih_f[l] = (f16*)(p + off); off += (size_t)wih_sz[l] * 2;
    whh_f[l] = (f16*)(p + off); off += (size_t)NG * NH * 2;
  }
  f16* xf16 = (f16*)(p + off); off += (size_t)NB * NT * ND * 2;
  f16* h = (f16*)(p + off); off += (size_t)NB * NT * NH * 2;
  u32* exq[3];
  for (int l = 0; l < 3; l++) {
    exq[l] = (u32*)(p + off); off += (size_t)2 * PL * 4;
  }
  f16* gxbuf[3];
  for (int s = 0; s < 3; s++) {
    gxbuf[s] = (f16*)(p + off); off += (size_t)NB * Tc * NG * 2;
  }

  hipMemsetAsync(ctrl, 0, 32768, stream);

  // all conversions in one dispatch
  k_conv_all<<<dim3(2048), dim3(256), 0, stream>>>(
      x, xf16, NB * NT * ND,
      w_ih[0], wih_f[0], wih_sz[0], w_hh[0], whh_f[0], NG * NH,
      w_ih[1], wih_f[1], wih_sz[1], w_hh[1], whh_f[1], NG * NH,
      w_ih[2], wih_f[2], wih_sz[2], w_hh[2], whh_f[2], NG * NH);

  const int mblocks = (NB * Tc) / 128;  // grid.y = NG/128 = 12

  // ---- anti-diagonal wavefront: diagonal d = {(l, d-l)}; <=3 units/launch ----
  for (int d = 0; d < 3 + nc - 1; d++) {
    int pl_[3], pc_[3], np = 0;
    for (int l = 0; l < 3; l++) {
      int c = d - l;
      if (c < 0 || c >= nc) continue;
      pl_[np] = l; pc_[np] = c; np++;
    }
    if (np == 0) continue;
    for (int s = 0; s < np; s++) {
      int l = pl_[s], c = pc_[s];
      if (l == 0)
        k_gemm2<ND><<<dim3(mblocks, 12), dim3(256), 0, stream>>>(
            xf16, wih_f[0], b_ih[0], gxbuf[s], c * Tc, tsh);
      else
        k_gemm2<NH><<<dim3(mblocks, 12), dim3(256), 0, stream>>>(
            h, wih_f[l], b_ih[l], gxbuf[s], c * Tc, tsh);
    }
    RecUnit us[3];
    for (int s = 0; s < np; s++) {
      int l = pl_[s], c = pc_[s];
      us[s].gx = gxbuf[s];
      us[s].whh = whh_f[l];
      us[s].bhh = b_hh[l];
      us[s].exq = exq[l];
      us[s].fl = ctrl + l * 512;
      us[s].t0 = c * Tc;
      us[s].bar_base = c * (Tc - 1);
    }
    for (int s = np; s < 3; s++) us[s] = us[0];
    k_rec<<<dim3(np * 128), dim3(256), 0, stream>>>(us[0], us[1], us[2], h, Tc);
  }
  k_fc<<<dim3(NB), dim3(64), 0, stream>>>(h, fcw, fcb, (float*)d_out);
}